// Round 6
// baseline (174.761 us; speedup 1.0000x reference)
//
#include <hip/hip_runtime.h>

#define S_  512
#define B_  256
#define NIN 180

// ---- DPP ctrl encodings (verified on HW in r5) ----
#define QP_X1 0xB1   // quad_perm -> lane i reads i^1
#define QP_X2 0x4E   // i^2
#define QP_X3 0x1B   // i^3
#define ROR4  0x124  // row rotate 4 (== xor4 on 8-periodic data)
#define ROR8  0x128  // row rotate 8 (== xor8 within each 16-lane row)

template<int CTRL>
__device__ __forceinline__ float dppf(float x) {
    return __uint_as_float((unsigned)__builtin_amdgcn_update_dpp(
        0, (int)__float_as_uint(x), CTRL, 0xF, 0xF, true));
}

// ======================= Kernel A: input GEMM =======================
// Layout for scan (16 lanes/chain, 4 chains/group):
// xg[(s*64 + b/4)*128 + (q>=2)*64 + (b&3)*16 + (q&1)*8 + (g&7)] =
//   s(g) * (x[s,b,:]·w_ih0[g,:] + b_ih0[g]+b_hh0[g]),  q = g>>3
__global__ __launch_bounds__(256) void xg_gemm(
    const float* __restrict__ x, const float* __restrict__ w,
    const float* __restrict__ bi, const float* __restrict__ bh,
    float* __restrict__ xg)
{
    __shared__ float wt[NIN][32];   // transposed + pre-scaled by s(g)
    __shared__ float bias[32];
    const int tid = threadIdx.x;
    for (int idx = tid; idx < NIN * 32; idx += 256) {
        int g = idx / NIN, i = idx - g * NIN;
        float s = ((g >> 3) == 2) ? -2.8853900817779268f : -1.4426950408889634f;
        wt[i][g] = s * w[idx];
    }
    if (tid < 32) {
        float s = ((tid >> 3) == 2) ? -2.8853900817779268f : -1.4426950408889634f;
        bias[tid] = s * (bi[tid] + bh[tid]);
    }
    __syncthreads();

    const int rg   = tid >> 3;        // 0..31 -> 4 rows each
    const int gq   = tid & 7;         // gate quad
    const int s    = blockIdx.x >> 1;
    const int half = blockIdx.x & 1;
    const int b0   = half * 128 + rg * 4;
    const float* xr = x + ((size_t)s * B_ + b0) * NIN;

    float4 acc[4];
    #pragma unroll
    for (int rr = 0; rr < 4; ++rr) acc[rr] = float4{0.f, 0.f, 0.f, 0.f};

    float4 xv[4];
    #pragma unroll
    for (int rr = 0; rr < 4; ++rr) xv[rr] = *(const float4*)(xr + (size_t)rr * NIN);

    #pragma unroll 3
    for (int ii = 0; ii < 45; ++ii) {
        // register prefetch of next iteration's x (clamped to stay in bounds)
        float4 xn[4];
        const int nx = (ii < 44) ? (ii + 1) : 44;
        #pragma unroll
        for (int rr = 0; rr < 4; ++rr)
            xn[rr] = *(const float4*)(xr + (size_t)rr * NIN + 4 * nx);
        #pragma unroll
        for (int e = 0; e < 4; ++e) {
            float4 wv = *(const float4*)&wt[4 * ii + e][gq * 4];
            #pragma unroll
            for (int rr = 0; rr < 4; ++rr) {
                float xe = (e == 0) ? xv[rr].x : (e == 1) ? xv[rr].y
                         : (e == 2) ? xv[rr].z : xv[rr].w;
                acc[rr].x = __builtin_fmaf(xe, wv.x, acc[rr].x);
                acc[rr].y = __builtin_fmaf(xe, wv.y, acc[rr].y);
                acc[rr].z = __builtin_fmaf(xe, wv.z, acc[rr].z);
                acc[rr].w = __builtin_fmaf(xe, wv.w, acc[rr].w);
            }
        }
        #pragma unroll
        for (int rr = 0; rr < 4; ++rr) xv[rr] = xn[rr];
    }

    float4 bv = *(const float4*)&bias[gq * 4];
    const int g0  = 4 * gq;
    const int q   = g0 >> 3;
    const int j0  = g0 & 7;                     // 0 or 4
    const int off = (q >> 1) * 64 + (q & 1) * 8 + j0;
    #pragma unroll
    for (int rr = 0; rr < 4; ++rr) {
        int b = b0 + rr;
        int bidc = b >> 2, cc = b & 3;
        float4 o = {acc[rr].x + bv.x, acc[rr].y + bv.y,
                    acc[rr].z + bv.z, acc[rr].w + bv.w};
        size_t addr = ((size_t)s * 64 + bidc) * 128 + off + cc * 16;
        *(float4*)(xg + addr) = o;
    }
}

// ======================= Kernel B: fused scan =======================
// 16 lanes/chain, 4 chains/wave. lane = cc*16 + b3*8 + j.
// Lane owns gate rows gA = b3*8+j (i/f) and gB = (2+b3)*8+j (g/o).
// ALL cross-lane via DPP within 16-lane rows (zero LDS-pipe ops).
// Pipeline: layer0(u) || layer1(u-1) || proj(u-2).
__global__ __launch_bounds__(64) void lstm_scan(
    const float* __restrict__ xg,
    const float* __restrict__ w_hh0,
    const float* __restrict__ w_ih1, const float* __restrict__ w_hh1,
    const float* __restrict__ b_ih1, const float* __restrict__ b_hh1,
    const float* __restrict__ w_reg, const float* __restrict__ b_reg,
    float* __restrict__ out)
{
    const int lt = threadIdx.x;
    const int j  = lt & 7;
    const int b3 = (lt >> 3) & 1;
    const int cc = lt >> 4;            // 0..3 chain within wave
    const bool b3z = (b3 == 0);
    const bool isl = (j == 0);
    const int bid   = blockIdx.x;      // 0..63
    const int chain = bid * 4 + cc;

    const int gA = b3 * 8 + j;         // class q=b3   (i or f)  - sigmoid
    const int gB = (2 + b3) * 8 + j;   // class q=2+b3 (g or o)  - tanh / sigmoid

    const float sSig  = -1.4426950408889634f;
    const float sTanh = -2.8853900817779268f;
    const float sB = b3z ? sTanh : sSig;
    const float aB = b3z ? 2.0f : 1.0f;
    const float bB = b3z ? -1.0f : 0.0f;

    float w0A[8], w0B[8], wi1A[8], wi1B[8], wh1A[8], wh1B[8], wrl[8];
    #pragma unroll
    for (int m = 0; m < 8; ++m) {
        int k = j ^ m;
        w0A[m]  = sSig * w_hh0[gA * 8 + k];
        w0B[m]  = sB   * w_hh0[gB * 8 + k];
        wi1A[m] = sSig * w_ih1[gA * 8 + k];
        wi1B[m] = sB   * w_ih1[gB * 8 + k];
        wh1A[m] = sSig * w_hh1[gA * 8 + k];
        wh1B[m] = sB   * w_hh1[gB * 8 + k];
        wrl[m]  = w_reg[b3 * 8 + k];   // projection column = b3
    }
    const float b1A = sSig * (b_ih1[gA] + b_hh1[gA]);
    const float b1B = sB   * (b_ih1[gB] + b_hh1[gB]);
    const float br  = b_reg[b3];

    auto sig = [](float a) {           // input pre-scaled by sSig
        return __builtin_amdgcn_rcpf(1.0f + __builtin_amdgcn_exp2f(a));
    };
    auto actB = [&](float a) {         // tanh (b3=0) / sigmoid (b3=1), pre-scaled
        return __builtin_fmaf(aB, __builtin_amdgcn_rcpf(1.0f + __builtin_amdgcn_exp2f(a)), bB);
    };
    auto tanhc = [](float c) {
        return __builtin_fmaf(2.0f, __builtin_amdgcn_rcpf(
            1.0f + __builtin_amdgcn_exp2f(-2.8853900817779268f * c)), -1.0f);
    };
    // r[m] = h[j^m] (h 8-periodic within each 16-lane row)
    auto ROTS = [&](float h, float* r) {
        r[0] = h;
        r[1] = dppf<QP_X1>(h);
        r[2] = dppf<QP_X2>(h);
        r[3] = dppf<QP_X3>(h);
        r[4] = dppf<ROR4>(h);
        r[5] = dppf<QP_X1>(r[4]);
        r[6] = dppf<QP_X2>(r[4]);
        r[7] = dppf<QP_X3>(r[4]);
    };
    // tA: i (b3=0) / f (b3=1); tB: g (b3=0) / o (b3=1). Pure-DPP combine.
    auto COMBINE2 = [&](float tA, float tB, float& c, float& h) {
        float m  = tA * tB;            // i*g on b3=0 lanes
        float mr = dppf<ROR8>(m);
        float fa = dppf<ROR8>(tA);     // f -> b3=0 lanes
        float ob = dppf<ROR8>(tB);     // o -> b3=0 lanes
        float ig = b3z ? m  : mr;
        float f  = b3z ? fa : tA;
        float o  = b3z ? ob : tB;
        c = __builtin_fmaf(f, c, ig);
        h = o * tanhc(c);
    };

    float h0p = 0.f, h1p = 0.f, c0 = 0.f, c1 = 0.f;

    const float* xb = xg + (size_t)bid * 128 + lt;
    float xqA[8], xqB[8];
    #pragma unroll
    for (int k = 0; k < 8; ++k) {
        xqA[k] = xb[(size_t)k * 8192];
        xqB[k] = xb[(size_t)k * 8192 + 64];
    }
    const float* xp = xb + (size_t)8 * 8192;
    float* op = out + (size_t)chain * 2 + b3;

    auto STEP = [&](float& xrA, float& xrB, bool l1on, bool doproj, bool pref) {
        float r0[8], r1[8];
        ROTS(h0p, r0);      // h0(u-1)
        ROTS(h1p, r1);      // h1(u-2)
        float a0A = xrA, a0B = xrB;
        if (pref) { xrA = xp[0]; xrB = xp[64]; xp += 8192; }
        #pragma unroll
        for (int m = 0; m < 8; ++m) {
            a0A = __builtin_fmaf(w0A[m], r0[m], a0A);
            a0B = __builtin_fmaf(w0B[m], r0[m], a0B);
        }
        float tA0 = sig(a0A), tB0 = actB(a0B);

        float a1A = b1A, a1B = b1B;
        float s1A = wh1A[0] * r1[0], s1B = wh1B[0] * r1[0];
        #pragma unroll
        for (int m = 0; m < 8; ++m) {
            a1A = __builtin_fmaf(wi1A[m], r0[m], a1A);
            a1B = __builtin_fmaf(wi1B[m], r0[m], a1B);
        }
        #pragma unroll
        for (int m = 1; m < 8; ++m) {
            s1A = __builtin_fmaf(wh1A[m], r1[m], s1A);
            s1B = __builtin_fmaf(wh1B[m], r1[m], s1B);
        }
        float tA1 = sig(a1A + s1A), tB1 = actB(a1B + s1B);

        if (doproj) {
            float p = br;
            #pragma unroll
            for (int m = 0; m < 8; ++m) p = __builtin_fmaf(wrl[m], r1[m], p);
            if (isl) *op = p;
            op += B_ * 2;
        }
        COMBINE2(tA0, tB0, c0, h0p);              // -> h0(u)
        if (l1on) COMBINE2(tA1, tB1, c1, h1p);    // -> h1(u-1)
    };

    // prologue u=0..7
    #pragma unroll
    for (int k = 0; k < 8; ++k) STEP(xqA[k], xqB[k], k > 0, k >= 2, true);
    // main u=8..503
    for (int tb = 8; tb < 504; tb += 8) {
        #pragma unroll
        for (int k = 0; k < 8; ++k) STEP(xqA[k], xqB[k], true, true, true);
    }
    // epilogue u=504..511 (no prefetch)
    #pragma unroll
    for (int k = 0; k < 8; ++k) STEP(xqA[k], xqB[k], true, true, false);

    // tail: layer1(511) + proj(510), then proj(511)
    {
        float r0[8], r1[8];
        ROTS(h0p, r0);      // h0(511)
        ROTS(h1p, r1);      // h1(510)
        float a1A = b1A, a1B = b1B;
        #pragma unroll
        for (int m = 0; m < 8; ++m) {
            a1A = __builtin_fmaf(wi1A[m], r0[m], a1A);
            a1B = __builtin_fmaf(wi1B[m], r0[m], a1B);
        }
        #pragma unroll
        for (int m = 0; m < 8; ++m) {
            a1A = __builtin_fmaf(wh1A[m], r1[m], a1A);
            a1B = __builtin_fmaf(wh1B[m], r1[m], a1B);
        }
        float tA1 = sig(a1A), tB1 = actB(a1B);

        float p = br;
        #pragma unroll
        for (int m = 0; m < 8; ++m) p = __builtin_fmaf(wrl[m], r1[m], p);
        if (isl) *op = p;           // row 510
        op += B_ * 2;

        COMBINE2(tA1, tB1, c1, h1p);   // h1(511)
        float r2[8];
        ROTS(h1p, r2);
        float p2 = br;
        #pragma unroll
        for (int m = 0; m < 8; ++m) p2 = __builtin_fmaf(wrl[m], r2[m], p2);
        if (isl) *op = p2;          // row 511
    }
}

extern "C" void kernel_launch(void* const* d_in, const int* in_sizes, int n_in,
                              void* d_out, int out_size, void* d_ws, size_t ws_size,
                              hipStream_t stream) {
    (void)in_sizes; (void)n_in; (void)out_size; (void)ws_size;
    const float* x     = (const float*)d_in[0];
    const float* w_ih0 = (const float*)d_in[1];
    const float* w_hh0 = (const float*)d_in[2];
    const float* b_ih0 = (const float*)d_in[3];
    const float* b_hh0 = (const float*)d_in[4];
    const float* w_ih1 = (const float*)d_in[5];
    const float* w_hh1 = (const float*)d_in[6];
    const float* b_ih1 = (const float*)d_in[7];
    const float* b_hh1 = (const float*)d_in[8];
    const float* w_reg = (const float*)d_in[9];
    const float* b_reg = (const float*)d_in[10];
    float* out = (float*)d_out;
    float* xg  = (float*)d_ws;   // 512*64*128*4 = 16 MB scratch

    xg_gemm<<<1024, 256, 0, stream>>>(x, w_ih0, b_ih0, b_hh0, xg);
    lstm_scan<<<64, 64, 0, stream>>>(xg, w_hh0, w_ih1, w_hh1, b_ih1, b_hh1,
                                     w_reg, b_reg, out);
}